// Round 1
// baseline (551.345 us; speedup 1.0000x reference)
//
#include <hip/hip_runtime.h>

#define N_NODES 100000
#define N_EDGES 1250000
#define IN_CH 64
#define HID 128
#define OUT_CH 2
#define NUM_GRAPHS 128

// ---------------------------------------------------------------------------
// K1: edge scatter. One wave (64 lanes) per edge; lane = input channel.
// agg[dst][c] += x[src][c]; cnt[dst] += 1.
// ---------------------------------------------------------------------------
__global__ __launch_bounds__(256) void scatter_k(const float* __restrict__ x,
                                                 const int* __restrict__ ei,
                                                 float* __restrict__ agg,
                                                 float* __restrict__ cnt) {
    const int lane = threadIdx.x & 63;
    const int wave = (int)((blockIdx.x * blockDim.x + threadIdx.x) >> 6);
    const int nwaves = (int)((gridDim.x * blockDim.x) >> 6);
    for (int e = wave; e < N_EDGES; e += nwaves) {
        const int src = ei[e];
        const int dst = ei[N_EDGES + e];
        const float v = x[(size_t)src * IN_CH + lane];
        atomicAdd(&agg[(size_t)dst * IN_CH + lane], v);
        if (lane == 0) atomicAdd(&cnt[dst], 1.0f);
    }
}

// ---------------------------------------------------------------------------
// K2: fused  h = relu(mean @ W_l^T + b_l + x @ W_r^T)  +  per-graph max pool.
// 256 threads = 2 groups x 128 output channels. Each group processes one node
// per iteration (group 0: even offsets, group 1: odd). Weights in registers.
// batch is sorted -> running max per (thread, graph), flush on graph change.
// relu => h >= 0, so uint atomicMax on float bits is order-correct, init 0.
// ---------------------------------------------------------------------------
__global__ __launch_bounds__(256) void node_k(const float* __restrict__ x,
                                              const float* __restrict__ agg,
                                              const float* __restrict__ cnt,
                                              const float* __restrict__ W_l,
                                              const float* __restrict__ b_l,
                                              const float* __restrict__ W_r,
                                              const int* __restrict__ batch,
                                              unsigned int* __restrict__ gmax) {
    __shared__ float4 smem[2][2][IN_CH / 4];  // [group][mean|x][k4]

    const int tid = (int)threadIdx.x;
    const int grp = tid >> 7;
    const int o = tid & 127;  // output channel

    float4 wl[16], wr[16];
#pragma unroll
    for (int k = 0; k < 16; ++k) {
        wl[k] = reinterpret_cast<const float4*>(W_l)[o * 16 + k];
        wr[k] = reinterpret_cast<const float4*>(W_r)[o * 16 + k];
    }
    const float bias = b_l[o];

    const int chunk = (N_NODES + gridDim.x - 1) / gridDim.x;
    const int start = (int)blockIdx.x * chunk;
    const int end = min(N_NODES, start + chunk);
    const int iters = (chunk + 1) >> 1;

    int cur_g = -1;
    float hmax = 0.0f;

    for (int i = 0; i < iters; ++i) {
        const int n = start + 2 * i + grp;
        const bool valid = (n < end);
        if (valid && o < IN_CH) {
            const float c = cnt[n];
            const float rcp = 1.0f / fmaxf(c, 1.0f);
            const float m = agg[(size_t)n * IN_CH + o] * rcp;
            const float xv = x[(size_t)n * IN_CH + o];
            ((float*)&smem[grp][0][0])[o] = m;
            ((float*)&smem[grp][1][0])[o] = xv;
        }
        __syncthreads();
        if (valid) {
            float acc = bias;
#pragma unroll
            for (int k = 0; k < 16; ++k) {
                const float4 m4 = smem[grp][0][k];
                const float4 x4 = smem[grp][1][k];
                acc += wl[k].x * m4.x + wl[k].y * m4.y + wl[k].z * m4.z + wl[k].w * m4.w;
                acc += wr[k].x * x4.x + wr[k].y * x4.y + wr[k].z * x4.z + wr[k].w * x4.w;
            }
            const float h = fmaxf(acc, 0.0f);
            const int gid = batch[n];
            if (gid != cur_g) {
                if (cur_g >= 0)
                    atomicMax(&gmax[(size_t)cur_g * HID + o], __float_as_uint(hmax));
                cur_g = gid;
                hmax = 0.0f;
            }
            hmax = fmaxf(hmax, h);
        }
        __syncthreads();
    }
    if (cur_g >= 0) atomicMax(&gmax[(size_t)cur_g * HID + o], __float_as_uint(hmax));
}

// ---------------------------------------------------------------------------
// K3: out[g][oc] = gmax[g] . W_lin[oc] + b_lin[oc].  128x2 outputs, 1 block.
// ---------------------------------------------------------------------------
__global__ __launch_bounds__(256) void head_k(const unsigned int* __restrict__ gmax_u,
                                              const float* __restrict__ W_lin,
                                              const float* __restrict__ b_lin,
                                              float* __restrict__ out) {
    const int t = (int)threadIdx.x;  // 256 = 128 graphs x 2 outputs
    const int g = t >> 1;
    const int oc = t & 1;
    const float* gm = (const float*)gmax_u;
    float acc = b_lin[oc];
#pragma unroll 4
    for (int k = 0; k < HID; ++k) acc += gm[(size_t)g * HID + k] * W_lin[oc * HID + k];
    out[(size_t)g * OUT_CH + oc] = acc;
}

extern "C" void kernel_launch(void* const* d_in, const int* in_sizes, int n_in,
                              void* d_out, int out_size, void* d_ws, size_t ws_size,
                              hipStream_t stream) {
    const float* x = (const float*)d_in[0];
    const float* W_l = (const float*)d_in[1];
    const float* b_l = (const float*)d_in[2];
    const float* W_r = (const float*)d_in[3];
    const float* W_lin = (const float*)d_in[4];
    const float* b_lin = (const float*)d_in[5];
    const int* ei = (const int*)d_in[6];
    const int* batch = (const int*)d_in[7];
    float* out = (float*)d_out;

    char* ws = (char*)d_ws;
    float* agg = (float*)ws;  // N_NODES * IN_CH floats
    float* cnt = (float*)(ws + (size_t)N_NODES * IN_CH * sizeof(float));
    unsigned int* gmax =
        (unsigned int*)(ws + (size_t)N_NODES * IN_CH * sizeof(float) +
                        (size_t)N_NODES * sizeof(float));

    hipMemsetAsync(agg, 0, (size_t)N_NODES * IN_CH * sizeof(float), stream);
    hipMemsetAsync(cnt, 0, (size_t)N_NODES * sizeof(float), stream);
    hipMemsetAsync(gmax, 0, (size_t)NUM_GRAPHS * HID * sizeof(float), stream);

    scatter_k<<<4096, 256, 0, stream>>>(x, ei, agg, cnt);
    node_k<<<1024, 256, 0, stream>>>(x, agg, cnt, W_l, b_l, W_r, batch, gmax);
    head_k<<<1, 256, 0, stream>>>(gmax, W_lin, b_lin, out);
}